// Round 9
// baseline (427.466 us; speedup 1.0000x reference)
//
#include <hip/hip_runtime.h>
#include <math.h>

constexpr int NN = 4096, DD = 64, TT = 60, HH = 128, GG = 512, KK = 192;

typedef _Float16 h8 __attribute__((ext_vector_type(8)));
typedef float f4 __attribute__((ext_vector_type(4)));

// ws layout (float offsets)
constexpr size_t XNT = 0;                                  // half [T][N][D] RAW x fp16; REUSED later as swizzled hbn16
constexpr size_t WFRG = (size_t)TT * NN * DD / 2;          // half [w][g][ks][lane][8] = 98304 halves (sc1-folded)
constexpr size_t BSUM = WFRG + 98304 / 2;                  // [512] f32 folded bias
constexpr size_t SC1 = BSUM + GG;                          // [64] (unused globally now)
constexpr size_t SH1 = SC1 + DD;                           // [64]
constexpr size_t HID = SH1 + DD;                           // [N][H] f32
constexpr size_t HBN = HID + (size_t)NN * HH;              // [N][H]
constexpr size_t SC2 = HBN + (size_t)NN * HH;              // [128]
constexpr size_t SH2 = SC2 + HH;
constexpr size_t U1O = SH2 + HH;
constexpr size_t U2O = U1O + HH;
constexpr size_t CCO = U2O + HH;                           // [4]: c1, c2, s1max(encoded uint)
constexpr size_t S1O = CCO + 4;                            // [N]
constexpr size_t S2O = S1O + NN;
constexpr size_t H2O = S2O + NN;                           // (unused)
constexpr size_t SSUM = H2O + (size_t)NN * HH;             // [0:64) bn1 sum, [64:128) bn1 sumsq,
                                                           // 128 bn1 ctr, 129 bn2 ctr,
                                                           // [132:260) bn2 sum, [260:388) bn2 sumsq

__device__ __forceinline__ float sigmoidf_(float x) { return 1.f / (1.f + __expf(-x)); }
__device__ __forceinline__ float tanhfast_(float x) { return 1.f - 2.f / (__expf(2.f * x) + 1.f); }
__device__ __forceinline__ float leakyf_(float z) { return fmaxf(z, 0.01f * z); }

__device__ __forceinline__ unsigned fenc_(float f) {
    unsigned b = __float_as_uint(f);
    return (b & 0x80000000u) ? ~b : (b | 0x80000000u);
}
__device__ __forceinline__ float fdec_(unsigned u) {
    return (u & 0x80000000u) ? __uint_as_float(u & 0x7fffffffu) : __uint_as_float(~u);
}

constexpr int TSTR = 264;  // halves per t-row in staging LDS (528 B: 2-way max bank aliasing)

// ---- k_pre: blocks [0,1024) = BN1 stats + coalesced fp16 transpose of x;
//      LAST stats block additionally: finalize sc1/sh1 -> weight swizzle (sc1-folded)
//      + bias fold. Block 1024 = u/v/c attention prep ----
__global__ __launch_bounds__(256) void k_pre(const float* __restrict__ x,
                                             const float* __restrict__ g1,
                                             const float* __restrict__ b1,
                                             const float* __restrict__ Wih,
                                             const float* __restrict__ Whh,
                                             const float* __restrict__ bih,
                                             const float* __restrict__ bhh,
                                             const float* __restrict__ Wt,
                                             const float* __restrict__ bt,
                                             const float* __restrict__ a,
                                             float* __restrict__ ws) {
    int b = blockIdx.x;
    int tid = threadIdx.x;
    if (b == 1024) {
        int k = tid;
        if (k < HH) {
            float u1 = 0.f, u2 = 0.f;
            for (int j = 0; j < HH; j++) {
                float w = Wt[j * HH + k];
                u1 = fmaf(w, a[j], u1);
                u2 = fmaf(w, a[HH + j], u2);
            }
            ws[U1O + k] = u1;
            ws[U2O + k] = u2;
            if (k == 0) {
                float c1 = 0.f, c2 = 0.f;
                for (int j = 0; j < HH; j++) {
                    c1 = fmaf(bt[j], a[j], c1);
                    c2 = fmaf(bt[j], a[HH + j], c2);
                }
                ws[CCO] = c1;
                ws[CCO + 1] = c2;
                ((unsigned*)ws)[CCO + 2] = fenc_(-1e30f);
            }
        }
        return;
    }
    // ---- xstats: rows n0..n0+3; coalesced reads; LDS [t][k] staging; b64 copy-out ----
    __shared__ _Float16 stg[TT * TSTR];
    __shared__ float rs[256], rss[256];
    __shared__ float scs[64], shs[64];
    __shared__ unsigned done;
    const float4* xb = (const float4*)(x + (size_t)b * 15360);
#pragma unroll
    for (int q = 0; q < 15; q++) {
        int f = q * 256 + tid;
        float4 v = xb[f];
        int k = f / 15, t0 = (f - k * 15) * 4;
        stg[(t0 + 0) * TSTR + k] = (_Float16)v.x;
        stg[(t0 + 1) * TSTR + k] = (_Float16)v.y;
        stg[(t0 + 2) * TSTR + k] = (_Float16)v.z;
        stg[(t0 + 3) * TSTR + k] = (_Float16)v.w;
    }
    __syncthreads();
    {
        int k = tid;
        float s = 0.f, ss = 0.f;
#pragma unroll
        for (int t = 0; t < TT; t++) {
            float v = (float)stg[t * TSTR + k];
            s += v;
            ss = fmaf(v, v, ss);
        }
        rs[tid] = s; rss[tid] = ss;
    }
    __syncthreads();
    if (tid < 64) {
        float ts = rs[tid] + rs[64 + tid] + rs[128 + tid] + rs[192 + tid];
        float tss = rss[tid] + rss[64 + tid] + rss[128 + tid] + rss[192 + tid];
        atomicAdd(&ws[SSUM + tid], ts);
        atomicAdd(&ws[SSUM + 64 + tid], tss);
    }
    __syncthreads();
    if (tid == 0) {
        __threadfence();
        done = atomicAdd((unsigned*)(ws + SSUM) + 128, 1u);
    }
    __syncthreads();
    // copy-out: xnT[t][n0..n0+3][0..63]
    _Float16* outp = (_Float16*)ws;
    int n0 = b * 4;
    for (int p = tid; p < 3840; p += 256) {
        int t = p >> 6, i = p & 63;
        *(uint2*)(outp + ((size_t)t * NN + n0) * DD + i * 4) =
            *(const uint2*)(stg + t * TSTR + i * 4);
    }
    if (done != 1023u) return;
    // ---- last block: finalize BN1 -> swizzle weights (sc1-folded) + bias fold ----
    __threadfence();
    if (tid < 64) {
        float cnt = (float)(NN * TT);
        float m = ws[SSUM + tid] / cnt;
        float var = ws[SSUM + 64 + tid] / cnt - m * m;
        float sc = g1[tid] * rsqrtf(var + 1e-5f);
        scs[tid] = sc;
        shs[tid] = b1[tid] - m * sc;
    }
    __syncthreads();
    _Float16* wf = (_Float16*)(ws + WFRG);
    for (int o = tid; o < 98304; o += 256) {
        int j = o & 7;
        int lane = (o >> 3) & 63;
        int rest = o >> 9;
        int ks = rest % 6;
        int gw = rest / 6;
        int g = gw & 3, w = gw >> 2;
        int col = g * 128 + w * 16 + (lane & 15);
        int k = ks * 32 + (lane >> 4) * 8 + j;
        float v = (k < DD) ? Wih[col * DD + k] * scs[k] : Whh[col * HH + (k - DD)];
        wf[o] = (_Float16)v;
    }
    for (int c = tid; c < GG; c += 256) {
        float bsum = bih[c] + bhh[c];
        const float4* wr = (const float4*)(Wih + c * 64);
#pragma unroll
        for (int q = 0; q < 16; q++) {
            float4 wv = wr[q];
            bsum = fmaf(wv.x, shs[q * 4], fmaf(wv.y, shs[q * 4 + 1],
                   fmaf(wv.z, shs[q * 4 + 2], fmaf(wv.w, shs[q * 4 + 3], bsum))));
        }
        ws[BSUM + c] = bsum;
    }
}

// ---- LSTM: MFMA, weights persistent in VGPRs (pre-folded; R6-proven prologue);
//      epilogue: HID write + BN2 partial sums + last-block BN2 finalize ----
__global__ __launch_bounds__(512, 1) void k_lstm(const float* __restrict__ g2,
                                                 const float* __restrict__ b2,
                                                 float* __restrict__ ws) {
    int tid = threadIdx.x;
    int w = tid >> 6, lane = tid & 63;
    int quad = lane >> 4, m = lane & 15;
    int r0 = blockIdx.x * 16;
    __shared__ _Float16 hlds[2][16][136];
    __shared__ unsigned dn;
    const _Float16* wf = (const _Float16*)(ws + WFRG);

    h8 bw[4][6];
#pragma unroll
    for (int g = 0; g < 4; g++)
#pragma unroll
        for (int ks = 0; ks < 6; ks++)
            bw[g][ks] = *(const h8*)(wf + ((((w * 4 + g) * 6 + ks) * 64 + lane) * 8));

    float bias[4];
#pragma unroll
    for (int g = 0; g < 4; g++) bias[g] = ws[BSUM + g * 128 + w * 16 + m];

    for (int p = tid; p < 2 * 16 * 136; p += 512) ((_Float16*)hlds)[p] = (_Float16)0.f;

    f4 cst = {};
    float hv[4];
    const _Float16* xb = (const _Float16*)ws + (size_t)(r0 + m) * DD + quad * 8;
    __syncthreads();

    h8 ax0 = *(const h8*)xb;
    h8 ax1 = *(const h8*)(xb + 32);

    for (int t = 0; t < TT; t++) {
        h8 ah[4];
        const _Float16* hb = &hlds[(t + 1) & 1][m][quad * 8];
#pragma unroll
        for (int ks = 0; ks < 4; ks++) ah[ks] = *(const h8*)(hb + ks * 32);
        h8 nx0 = {}, nx1 = {};
        if (t + 1 < TT) {
            const _Float16* xp = xb + (size_t)(t + 1) * NN * DD;
            nx0 = *(const h8*)xp;
            nx1 = *(const h8*)(xp + 32);
        }

        f4 acc[4];
#pragma unroll
        for (int g = 0; g < 4; g++) acc[g] = (f4){bias[g], bias[g], bias[g], bias[g]};
#pragma unroll
        for (int g = 0; g < 4; g++) acc[g] = __builtin_amdgcn_mfma_f32_16x16x32_f16(ax0, bw[g][0], acc[g], 0, 0, 0);
#pragma unroll
        for (int g = 0; g < 4; g++) acc[g] = __builtin_amdgcn_mfma_f32_16x16x32_f16(ax1, bw[g][1], acc[g], 0, 0, 0);
#pragma unroll
        for (int ks = 0; ks < 4; ks++)
#pragma unroll
            for (int g = 0; g < 4; g++)
                acc[g] = __builtin_amdgcn_mfma_f32_16x16x32_f16(ah[ks], bw[g][ks + 2], acc[g], 0, 0, 0);

#pragma unroll
        for (int r = 0; r < 4; r++) {
            float ig = sigmoidf_(acc[0][r]);
            float fg = sigmoidf_(acc[1][r]);
            float gg = tanhfast_(acc[2][r]);
            float og = sigmoidf_(acc[3][r]);
            float c = fmaf(fg, cst[r], ig * gg);
            cst[r] = c;
            hv[r] = og * tanhfast_(c);
        }
        _Float16* wbuf = &hlds[t & 1][0][0];
        int col = w * 16 + m;
#pragma unroll
        for (int r = 0; r < 4; r++) wbuf[(quad * 4 + r) * 136 + col] = (_Float16)hv[r];
        __syncthreads();
        ax0 = nx0; ax1 = nx1;
    }
    int col = w * 16 + m;
#pragma unroll
    for (int r = 0; r < 4; r++)
        ws[HID + (size_t)(r0 + quad * 4 + r) * HH + col] = hv[r];

    // BN2 partial sums (wave-local reduce, 1 atomic/col)
    float s = hv[0] + hv[1] + hv[2] + hv[3];
    float ss = fmaf(hv[0], hv[0], fmaf(hv[1], hv[1], fmaf(hv[2], hv[2], hv[3] * hv[3])));
    s += __shfl_xor(s, 16, 64); s += __shfl_xor(s, 32, 64);
    ss += __shfl_xor(ss, 16, 64); ss += __shfl_xor(ss, 32, 64);
    if (quad == 0) {
        atomicAdd(&ws[SSUM + 132 + col], s);
        atomicAdd(&ws[SSUM + 260 + col], ss);
    }
    __syncthreads();
    if (tid == 0) {
        __threadfence();
        dn = atomicAdd((unsigned*)(ws + SSUM) + 129, 1u);
    }
    __syncthreads();
    if (dn == 255u) {
        __threadfence();
        if (tid < 128) {
            float mm = ws[SSUM + 132 + tid] / (float)NN;
            float var = ws[SSUM + 260 + tid] / (float)NN - mm * mm;
            float sc = g2[tid] * rsqrtf(var + 1e-5f);
            ws[SC2 + tid] = sc;
            ws[SH2 + tid] = b2[tid] - mm * sc;
        }
    }
}

// ---- apply BN2: s1, s2, fp32 hbn, LDS-staged coalesced swizzled fp16 hbn, s1max ----
__global__ void k_hbn(float* __restrict__ ws) {
    __shared__ float sc[HH], sh[HH], u1s[HH], u2s[HH];
    __shared__ _Float16 swz[4096];
    int tid = threadIdx.x;
    if (tid < HH) {
        sc[tid] = ws[SC2 + tid]; sh[tid] = ws[SH2 + tid];
        u1s[tid] = ws[U1O + tid]; u2s[tid] = ws[U2O + tid];
    }
    __syncthreads();
    int r = tid >> 3, l = tid & 7;
    int n = blockIdx.x * 32 + r;
    const float* hr = ws + HID + (size_t)n * HH;
    float* hb = ws + HBN + (size_t)n * HH;
    int lanehi = (r >> 3);
    int jj = r & 7;
    float d1 = 0.f, d2 = 0.f;
    int k0 = l * 16;
#pragma unroll
    for (int q4 = 0; q4 < 4; q4++) {
        float4 hv4 = *(const float4*)&hr[k0 + q4 * 4];
        float4 o;
#pragma unroll
        for (int c = 0; c < 4; c++) {
            int kk = k0 + q4 * 4 + c;
            float v = fmaf(((const float*)&hv4)[c], sc[kk], sh[kk]);
            ((float*)&o)[c] = v;
            swz[l * 512 + (lanehi * 16 + (kk & 15)) * 8 + jj] = (_Float16)v;
            d1 = fmaf(v, u1s[kk], d1);
            d2 = fmaf(v, u2s[kk], d2);
        }
        *(float4*)&hb[k0 + q4 * 4] = o;
    }
#pragma unroll
    for (int o = 1; o < 8; o <<= 1) { d1 += __shfl_xor(d1, o, 64); d2 += __shfl_xor(d2, o, 64); }
    if (l == 0) {
        float s1 = d1 + ws[CCO];
        ws[S1O + n] = s1;
        ws[S2O + n] = d2 + ws[CCO + 1];
        atomicMax((unsigned*)ws + CCO + 2, fenc_(s1));
    }
    __syncthreads();
    _Float16* dst = (_Float16*)ws + (size_t)blockIdx.x * 4096;
    for (int p = tid; p < 512; p += 256)
        *(h8*)(dst + p * 8) = *(const h8*)(swz + p * 8);
}

// ---- attention + fc fused; waves split the j-range (exp dedup 8x -> 2x) ----
// wave w: jsplit = w&3 (1024 j's), hg-half = w>>2 (4 hgroups); LDS partial reduce
__global__ __launch_bounds__(512, 1) void k_attfc(const float* __restrict__ Wfc,
                                                  const float* __restrict__ bfc,
                                                  const float* __restrict__ Wout,
                                                  const float* __restrict__ bout,
                                                  float* __restrict__ ws,
                                                  float* __restrict__ out) {
    __shared__ float ls1[NN];           // 16 KB
    __shared__ float red[4][16][132];   // 33 KB partials
    __shared__ float psr[4][16];
    __shared__ float h2s[16][132];      // 8.4 KB
    int tid = threadIdx.x;
    int w = tid >> 6, lane = tid & 63;
    int quad = lane >> 4, m = lane & 15;
    int whalf = w >> 2, jsplit = w & 3;
    int n0 = blockIdx.x * 16;
    for (int i = tid; i < NN; i += 512) ls1[i] = ws[S1O + i];
    __syncthreads();
    float s1max = fdec_(((unsigned*)ws)[CCO + 2]);
    float s2n = ws[S2O + n0 + m];
    float mi = leakyf_(s2n + s1max);
    const _Float16* hbsw = (const _Float16*)ws;
    f4 acc[4] = {};
    float psum = 0.f;
    for (int jt0 = 0; jt0 < 32; jt0++) {
        int jt = jsplit * 32 + jt0;
        const float* sp = &ls1[jt * 32 + quad * 8];
        h8 ap;
        float ps = 0.f;
#pragma unroll
        for (int jj = 0; jj < 8; jj++) {
            float z = s2n + sp[jj];
            float p = __expf(leakyf_(z) - mi);
            ps += p;
            ap[jj] = (_Float16)p;
        }
        psum += ps;
#pragma unroll
        for (int hgi = 0; hgi < 4; hgi++) {
            int hg = whalf * 4 + hgi;
            h8 bb = *(const h8*)(hbsw + ((size_t)(jt * 8 + hg) * 64 + lane) * 8);
            acc[hgi] = __builtin_amdgcn_mfma_f32_16x16x32_f16(ap, bb, acc[hgi], 0, 0, 0);
        }
    }
    psum += __shfl_xor(psum, 16, 64);
    psum += __shfl_xor(psum, 32, 64);
    if (whalf == 0 && lane < 16) psr[jsplit][lane] = psum;
#pragma unroll
    for (int hgi = 0; hgi < 4; hgi++) {
        int h = (whalf * 4 + hgi) * 16 + m;
#pragma unroll
        for (int r = 0; r < 4; r++)
            red[jsplit][quad * 4 + r][h] = acc[hgi][r];
    }
    __syncthreads();
    if (tid < 16) {
        float pt = psr[0][tid] + psr[1][tid] + psr[2][tid] + psr[3][tid];
        psr[0][tid] = 1.f / pt;
    }
    __syncthreads();
#pragma unroll
    for (int cc = 0; cc < 4; cc++) {
        int c = cc * 512 + tid;
        int row = c >> 7, h = c & 127;
        float v = red[0][row][h] + red[1][row][h] + red[2][row][h] + red[3][row][h];
        h2s[row][h] = fmaf(v, psr[0][row], ws[HBN + (size_t)(n0 + row) * HH + h]);
    }
    __syncthreads();
    int row = tid >> 5, jj = tid & 31;
    float po = 0.f;
#pragma unroll
    for (int q = 0; q < 4; q++) {
        int j = q * 32 + jj;
        const float4* wr = (const float4*)(Wfc + (size_t)j * HH);
        float a = 0.f;
#pragma unroll 8
        for (int kq = 0; kq < 32; kq++) {
            float4 wv = wr[kq];
            float4 hv = *(const float4*)&h2s[row][kq * 4];
            a = fmaf(wv.x, hv.x, fmaf(wv.y, hv.y, fmaf(wv.z, hv.z, fmaf(wv.w, hv.w, a))));
        }
        po = fmaf(leakyf_(a + bfc[j]), Wout[j], po);
    }
#pragma unroll
    for (int o = 1; o < 32; o <<= 1) po += __shfl_xor(po, o, 64);
    if (jj == 0) out[n0 + row] = 1.f / (1.f + __expf(-(po + bout[0])));
}

extern "C" void kernel_launch(void* const* d_in, const int* in_sizes, int n_in,
                              void* d_out, int out_size, void* d_ws, size_t ws_size,
                              hipStream_t stream) {
    const float* x = (const float*)d_in[0];
    const float* bn1_g = (const float*)d_in[1];
    const float* bn1_b = (const float*)d_in[2];
    const float* W_ih = (const float*)d_in[3];
    const float* W_hh = (const float*)d_in[4];
    const float* b_ih = (const float*)d_in[5];
    const float* b_hh = (const float*)d_in[6];
    const float* bn2_g = (const float*)d_in[7];
    const float* bn2_b = (const float*)d_in[8];
    const float* W_t = (const float*)d_in[9];
    const float* b_t = (const float*)d_in[10];
    const float* a = (const float*)d_in[11];
    const float* W_fc = (const float*)d_in[12];
    const float* b_fc = (const float*)d_in[13];
    const float* W_out = (const float*)d_in[14];
    const float* b_out = (const float*)d_in[15];
    float* ws = (float*)d_ws;
    float* out = (float*)d_out;

    hipMemsetAsync((char*)d_ws + SSUM * sizeof(float), 0, 392 * sizeof(float), stream);
    k_pre<<<1025, 256, 0, stream>>>(x, bn1_g, bn1_b, W_ih, W_hh, b_ih, b_hh, W_t, b_t, a, ws);
    k_lstm<<<NN / 16, 512, 0, stream>>>(bn2_g, bn2_b, ws);
    k_hbn<<<NN / 32, 256, 0, stream>>>(ws);
    k_attfc<<<NN / 16, 512, 0, stream>>>(W_fc, b_fc, W_out, b_out, ws, out);
}

// Round 10
// 332.176 us; speedup vs baseline: 1.2869x; 1.2869x over previous
//
#include <hip/hip_runtime.h>
#include <math.h>

constexpr int NN = 4096, DD = 64, TT = 60, HH = 128, GG = 512, KK = 192;

typedef _Float16 h8 __attribute__((ext_vector_type(8)));
typedef float f4 __attribute__((ext_vector_type(4)));

// ws layout (float offsets)
constexpr size_t XNT = 0;                                  // half [T][N][D] RAW x fp16; REUSED later as swizzled hbn16
constexpr size_t WFRG = (size_t)TT * NN * DD / 2;          // half [w][g][ks][lane][8] = 98304 halves (UNfolded)
constexpr size_t BSUM = WFRG + 98304 / 2;                  // [512] f32 folded bias
constexpr size_t SC1 = BSUM + GG;                          // [64] (scratch)
constexpr size_t SH1 = SC1 + DD;                           // [64]
constexpr size_t HID = SH1 + DD;                           // [N][H] f32
constexpr size_t HBN = HID + (size_t)NN * HH;              // [N][H]
constexpr size_t SC2 = HBN + (size_t)NN * HH;              // [128]
constexpr size_t SH2 = SC2 + HH;
constexpr size_t U1O = SH2 + HH;
constexpr size_t U2O = U1O + HH;
constexpr size_t CCO = U2O + HH;                           // [4]: c1, c2, s1max(encoded uint)
constexpr size_t S1O = CCO + 4;                            // [N]
constexpr size_t S2O = S1O + NN;
constexpr size_t H2O = S2O + NN;                           // (unused)
constexpr size_t SSUM = H2O + (size_t)NN * HH;             // [0:64) bn1 sum, [64:128) bn1 sumsq,
                                                           // 128 bn1 ctr, 129 bn2 ctr,
                                                           // [132:260) bn2 sum, [260:388) bn2 sumsq
constexpr size_t SC16 = SSUM + 392;                        // fp16[64] sc1 (32 floats)

__device__ __forceinline__ float sigmoidf_(float x) { return 1.f / (1.f + __expf(-x)); }
__device__ __forceinline__ float tanhfast_(float x) { return 1.f - 2.f / (__expf(2.f * x) + 1.f); }
__device__ __forceinline__ float leakyf_(float z) { return fmaxf(z, 0.01f * z); }

__device__ __forceinline__ unsigned fenc_(float f) {
    unsigned b = __float_as_uint(f);
    return (b & 0x80000000u) ? ~b : (b | 0x80000000u);
}
__device__ __forceinline__ float fdec_(unsigned u) {
    return (u & 0x80000000u) ? __uint_as_float(u & 0x7fffffffu) : __uint_as_float(~u);
}

constexpr int TSTR = 264;  // halves per t-row in staging LDS

// ---- k_pre: blocks [0,1024) BN1 stats + fp16 transpose; [1024,1408) weight swizzle
//      (UNfolded, parallel); 1408 u/v/c prep. Last stats block: finalize sc/sh,
//      write fp16 sc1 vector, fold bias (cheap). ----
__global__ __launch_bounds__(256) void k_pre(const float* __restrict__ x,
                                             const float* __restrict__ g1,
                                             const float* __restrict__ b1,
                                             const float* __restrict__ Wih,
                                             const float* __restrict__ Whh,
                                             const float* __restrict__ bih,
                                             const float* __restrict__ bhh,
                                             const float* __restrict__ Wt,
                                             const float* __restrict__ bt,
                                             const float* __restrict__ a,
                                             float* __restrict__ ws) {
    int b = blockIdx.x;
    int tid = threadIdx.x;
    if (b >= 1024) {
        if (b == 1408) {
            int k = tid;
            if (k < HH) {
                float u1 = 0.f, u2 = 0.f;
                for (int j = 0; j < HH; j++) {
                    float w = Wt[j * HH + k];
                    u1 = fmaf(w, a[j], u1);
                    u2 = fmaf(w, a[HH + j], u2);
                }
                ws[U1O + k] = u1;
                ws[U2O + k] = u2;
                if (k == 0) {
                    float c1 = 0.f, c2 = 0.f;
                    for (int j = 0; j < HH; j++) {
                        c1 = fmaf(bt[j], a[j], c1);
                        c2 = fmaf(bt[j], a[HH + j], c2);
                    }
                    ws[CCO] = c1;
                    ws[CCO + 1] = c2;
                    ((unsigned*)ws)[CCO + 2] = fenc_(-1e30f);
                }
            }
            return;
        }
        // parallel weight swizzle (UNfolded): frag (w,g,ks): W[k][col],
        // col=g*128+w*16+(lane&15), k=ks*32+(lane>>4)*8+j
        int o = (b - 1024) * 256 + tid;
        _Float16* wf = (_Float16*)(ws + WFRG);
        int j = o & 7;
        int lane = (o >> 3) & 63;
        int rest = o >> 9;
        int ks = rest % 6;
        int gw = rest / 6;
        int g = gw & 3, w = gw >> 2;
        int col = g * 128 + w * 16 + (lane & 15);
        int k = ks * 32 + (lane >> 4) * 8 + j;
        float v = (k < DD) ? Wih[col * DD + k] : Whh[col * HH + (k - DD)];
        wf[o] = (_Float16)v;
        return;
    }
    // ---- xstats: rows n0..n0+3; coalesced reads; LDS [t][k] staging; b64 copy-out ----
    __shared__ _Float16 stg[TT * TSTR];
    __shared__ float rs[256], rss[256];
    __shared__ float scs[64], shs[64];
    __shared__ unsigned done;
    const float4* xb = (const float4*)(x + (size_t)b * 15360);
#pragma unroll
    for (int q = 0; q < 15; q++) {
        int f = q * 256 + tid;
        float4 v = xb[f];
        int k = f / 15, t0 = (f - k * 15) * 4;
        stg[(t0 + 0) * TSTR + k] = (_Float16)v.x;
        stg[(t0 + 1) * TSTR + k] = (_Float16)v.y;
        stg[(t0 + 2) * TSTR + k] = (_Float16)v.z;
        stg[(t0 + 3) * TSTR + k] = (_Float16)v.w;
    }
    __syncthreads();
    {
        int k = tid;
        float s = 0.f, ss = 0.f;
#pragma unroll
        for (int t = 0; t < TT; t++) {
            float v = (float)stg[t * TSTR + k];
            s += v;
            ss = fmaf(v, v, ss);
        }
        rs[tid] = s; rss[tid] = ss;
    }
    __syncthreads();
    if (tid < 64) {
        float ts = rs[tid] + rs[64 + tid] + rs[128 + tid] + rs[192 + tid];
        float tss = rss[tid] + rss[64 + tid] + rss[128 + tid] + rss[192 + tid];
        atomicAdd(&ws[SSUM + tid], ts);
        atomicAdd(&ws[SSUM + 64 + tid], tss);
    }
    __syncthreads();
    if (tid == 0) {
        __threadfence();
        done = atomicAdd((unsigned*)(ws + SSUM) + 128, 1u);
    }
    __syncthreads();
    // copy-out: xnT[t][n0..n0+3][0..63]
    _Float16* outp = (_Float16*)ws;
    int n0 = b * 4;
    for (int p = tid; p < 3840; p += 256) {
        int t = p >> 6, i = p & 63;
        *(uint2*)(outp + ((size_t)t * NN + n0) * DD + i * 4) =
            *(const uint2*)(stg + t * TSTR + i * 4);
    }
    if (done != 1023u) return;
    // ---- last block: finalize BN1; fp16 sc1 vector; bias fold (cheap) ----
    __threadfence();
    if (tid < 64) {
        float cnt = (float)(NN * TT);
        float m = ws[SSUM + tid] / cnt;
        float var = ws[SSUM + 64 + tid] / cnt - m * m;
        float sc = g1[tid] * rsqrtf(var + 1e-5f);
        scs[tid] = sc;
        shs[tid] = b1[tid] - m * sc;
        ((_Float16*)(ws + SC16))[tid] = (_Float16)sc;
    }
    __syncthreads();
    for (int c = tid; c < GG; c += 256) {
        float bsum = bih[c] + bhh[c];
        const float4* wr = (const float4*)(Wih + c * 64);
#pragma unroll
        for (int q = 0; q < 16; q++) {
            float4 wv = wr[q];
            bsum = fmaf(wv.x, shs[q * 4], fmaf(wv.y, shs[q * 4 + 1],
                   fmaf(wv.z, shs[q * 4 + 2], fmaf(wv.w, shs[q * 4 + 3], bsum))));
        }
        ws[BSUM + c] = bsum;
    }
}

// ---- LSTM: MFMA, weights persistent in VGPRs (R6-proven prologue);
//      sc1 applied to x A-frags via packed fp16 muls; BN2 epilogue ----
__global__ __launch_bounds__(512, 1) void k_lstm(const float* __restrict__ g2,
                                                 const float* __restrict__ b2,
                                                 float* __restrict__ ws) {
    int tid = threadIdx.x;
    int w = tid >> 6, lane = tid & 63;
    int quad = lane >> 4, m = lane & 15;
    int r0 = blockIdx.x * 16;
    __shared__ _Float16 hlds[2][16][136];
    __shared__ unsigned dn;
    const _Float16* wf = (const _Float16*)(ws + WFRG);

    h8 bw[4][6];
#pragma unroll
    for (int g = 0; g < 4; g++)
#pragma unroll
        for (int ks = 0; ks < 6; ks++)
            bw[g][ks] = *(const h8*)(wf + ((((w * 4 + g) * 6 + ks) * 64 + lane) * 8));

    float bias[4];
#pragma unroll
    for (int g = 0; g < 4; g++) bias[g] = ws[BSUM + g * 128 + w * 16 + m];

    const _Float16* sc16 = (const _Float16*)(ws + SC16);
    h8 scv0 = *(const h8*)(sc16 + quad * 8);
    h8 scv1 = *(const h8*)(sc16 + 32 + quad * 8);

    for (int p = tid; p < 2 * 16 * 136; p += 512) ((_Float16*)hlds)[p] = (_Float16)0.f;

    f4 cst = {};
    float hv[4];
    const _Float16* xb = (const _Float16*)ws + (size_t)(r0 + m) * DD + quad * 8;
    __syncthreads();

    h8 ax0 = (*(const h8*)xb) * scv0;
    h8 ax1 = (*(const h8*)(xb + 32)) * scv1;

    for (int t = 0; t < TT; t++) {
        h8 ah[4];
        const _Float16* hb = &hlds[(t + 1) & 1][m][quad * 8];
#pragma unroll
        for (int ks = 0; ks < 4; ks++) ah[ks] = *(const h8*)(hb + ks * 32);
        h8 nx0 = {}, nx1 = {};
        if (t + 1 < TT) {
            const _Float16* xp = xb + (size_t)(t + 1) * NN * DD;
            nx0 = *(const h8*)xp;
            nx1 = *(const h8*)(xp + 32);
        }

        f4 acc[4];
#pragma unroll
        for (int g = 0; g < 4; g++) acc[g] = (f4){bias[g], bias[g], bias[g], bias[g]};
#pragma unroll
        for (int g = 0; g < 4; g++) acc[g] = __builtin_amdgcn_mfma_f32_16x16x32_f16(ax0, bw[g][0], acc[g], 0, 0, 0);
#pragma unroll
        for (int g = 0; g < 4; g++) acc[g] = __builtin_amdgcn_mfma_f32_16x16x32_f16(ax1, bw[g][1], acc[g], 0, 0, 0);
#pragma unroll
        for (int ks = 0; ks < 4; ks++)
#pragma unroll
            for (int g = 0; g < 4; g++)
                acc[g] = __builtin_amdgcn_mfma_f32_16x16x32_f16(ah[ks], bw[g][ks + 2], acc[g], 0, 0, 0);

#pragma unroll
        for (int r = 0; r < 4; r++) {
            float ig = sigmoidf_(acc[0][r]);
            float fg = sigmoidf_(acc[1][r]);
            float gg = tanhfast_(acc[2][r]);
            float og = sigmoidf_(acc[3][r]);
            float c = fmaf(fg, cst[r], ig * gg);
            cst[r] = c;
            hv[r] = og * tanhfast_(c);
        }
        _Float16* wbuf = &hlds[t & 1][0][0];
        int col = w * 16 + m;
#pragma unroll
        for (int r = 0; r < 4; r++) wbuf[(quad * 4 + r) * 136 + col] = (_Float16)hv[r];
        __syncthreads();
        ax0 = nx0 * scv0;
        ax1 = nx1 * scv1;
    }
    int col = w * 16 + m;
#pragma unroll
    for (int r = 0; r < 4; r++)
        ws[HID + (size_t)(r0 + quad * 4 + r) * HH + col] = hv[r];

    // BN2 partial sums (wave-local reduce, 1 atomic/col)
    float s = hv[0] + hv[1] + hv[2] + hv[3];
    float ss = fmaf(hv[0], hv[0], fmaf(hv[1], hv[1], fmaf(hv[2], hv[2], hv[3] * hv[3])));
    s += __shfl_xor(s, 16, 64); s += __shfl_xor(s, 32, 64);
    ss += __shfl_xor(ss, 16, 64); ss += __shfl_xor(ss, 32, 64);
    if (quad == 0) {
        atomicAdd(&ws[SSUM + 132 + col], s);
        atomicAdd(&ws[SSUM + 260 + col], ss);
    }
    __syncthreads();
    if (tid == 0) {
        __threadfence();
        dn = atomicAdd((unsigned*)(ws + SSUM) + 129, 1u);
    }
    __syncthreads();
    if (dn == 255u) {
        __threadfence();
        if (tid < 128) {
            float mm = ws[SSUM + 132 + tid] / (float)NN;
            float var = ws[SSUM + 260 + tid] / (float)NN - mm * mm;
            float sc = g2[tid] * rsqrtf(var + 1e-5f);
            ws[SC2 + tid] = sc;
            ws[SH2 + tid] = b2[tid] - mm * sc;
        }
    }
}

// ---- apply BN2: s1, s2, fp32 hbn, LDS-staged coalesced swizzled fp16 hbn, s1max ----
__global__ void k_hbn(float* __restrict__ ws) {
    __shared__ float sc[HH], sh[HH], u1s[HH], u2s[HH];
    __shared__ _Float16 swz[4096];
    int tid = threadIdx.x;
    if (tid < HH) {
        sc[tid] = ws[SC2 + tid]; sh[tid] = ws[SH2 + tid];
        u1s[tid] = ws[U1O + tid]; u2s[tid] = ws[U2O + tid];
    }
    __syncthreads();
    int r = tid >> 3, l = tid & 7;
    int n = blockIdx.x * 32 + r;
    const float* hr = ws + HID + (size_t)n * HH;
    float* hb = ws + HBN + (size_t)n * HH;
    int lanehi = (r >> 3);
    int jj = r & 7;
    float d1 = 0.f, d2 = 0.f;
    int k0 = l * 16;
#pragma unroll
    for (int q4 = 0; q4 < 4; q4++) {
        float4 hv4 = *(const float4*)&hr[k0 + q4 * 4];
        float4 o;
#pragma unroll
        for (int c = 0; c < 4; c++) {
            int kk = k0 + q4 * 4 + c;
            float v = fmaf(((const float*)&hv4)[c], sc[kk], sh[kk]);
            ((float*)&o)[c] = v;
            swz[l * 512 + (lanehi * 16 + (kk & 15)) * 8 + jj] = (_Float16)v;
            d1 = fmaf(v, u1s[kk], d1);
            d2 = fmaf(v, u2s[kk], d2);
        }
        *(float4*)&hb[k0 + q4 * 4] = o;
    }
#pragma unroll
    for (int o = 1; o < 8; o <<= 1) { d1 += __shfl_xor(d1, o, 64); d2 += __shfl_xor(d2, o, 64); }
    if (l == 0) {
        float s1 = d1 + ws[CCO];
        ws[S1O + n] = s1;
        ws[S2O + n] = d2 + ws[CCO + 1];
        atomicMax((unsigned*)ws + CCO + 2, fenc_(s1));
    }
    __syncthreads();
    _Float16* dst = (_Float16*)ws + (size_t)blockIdx.x * 4096;
    for (int p = tid; p < 512; p += 256)
        *(h8*)(dst + p * 8) = *(const h8*)(swz + p * 8);
}

// ---- attention + fc fused; waves split the j-range (exp dedup) ----
__global__ __launch_bounds__(512, 1) void k_attfc(const float* __restrict__ Wfc,
                                                  const float* __restrict__ bfc,
                                                  const float* __restrict__ Wout,
                                                  const float* __restrict__ bout,
                                                  float* __restrict__ ws,
                                                  float* __restrict__ out) {
    __shared__ float ls1[NN];
    __shared__ float red[4][16][132];
    __shared__ float psr[4][16];
    __shared__ float h2s[16][132];
    int tid = threadIdx.x;
    int w = tid >> 6, lane = tid & 63;
    int quad = lane >> 4, m = lane & 15;
    int whalf = w >> 2, jsplit = w & 3;
    int n0 = blockIdx.x * 16;
    for (int i = tid; i < NN; i += 512) ls1[i] = ws[S1O + i];
    __syncthreads();
    float s1max = fdec_(((unsigned*)ws)[CCO + 2]);
    float s2n = ws[S2O + n0 + m];
    float mi = leakyf_(s2n + s1max);
    const _Float16* hbsw = (const _Float16*)ws;
    f4 acc[4] = {};
    float psum = 0.f;
    for (int jt0 = 0; jt0 < 32; jt0++) {
        int jt = jsplit * 32 + jt0;
        const float* sp = &ls1[jt * 32 + quad * 8];
        h8 ap;
        float ps = 0.f;
#pragma unroll
        for (int jj = 0; jj < 8; jj++) {
            float z = s2n + sp[jj];
            float p = __expf(leakyf_(z) - mi);
            ps += p;
            ap[jj] = (_Float16)p;
        }
        psum += ps;
#pragma unroll
        for (int hgi = 0; hgi < 4; hgi++) {
            int hg = whalf * 4 + hgi;
            h8 bb = *(const h8*)(hbsw + ((size_t)(jt * 8 + hg) * 64 + lane) * 8);
            acc[hgi] = __builtin_amdgcn_mfma_f32_16x16x32_f16(ap, bb, acc[hgi], 0, 0, 0);
        }
    }
    psum += __shfl_xor(psum, 16, 64);
    psum += __shfl_xor(psum, 32, 64);
    if (whalf == 0 && lane < 16) psr[jsplit][lane] = psum;
#pragma unroll
    for (int hgi = 0; hgi < 4; hgi++) {
        int h = (whalf * 4 + hgi) * 16 + m;
#pragma unroll
        for (int r = 0; r < 4; r++)
            red[jsplit][quad * 4 + r][h] = acc[hgi][r];
    }
    __syncthreads();
    if (tid < 16) {
        float pt = psr[0][tid] + psr[1][tid] + psr[2][tid] + psr[3][tid];
        psr[0][tid] = 1.f / pt;
    }
    __syncthreads();
#pragma unroll
    for (int cc = 0; cc < 4; cc++) {
        int c = cc * 512 + tid;
        int row = c >> 7, h = c & 127;
        float v = red[0][row][h] + red[1][row][h] + red[2][row][h] + red[3][row][h];
        h2s[row][h] = fmaf(v, psr[0][row], ws[HBN + (size_t)(n0 + row) * HH + h]);
    }
    __syncthreads();
    int row = tid >> 5, jj = tid & 31;
    float po = 0.f;
#pragma unroll
    for (int q = 0; q < 4; q++) {
        int j = q * 32 + jj;
        const float4* wr = (const float4*)(Wfc + (size_t)j * HH);
        float a = 0.f;
#pragma unroll 8
        for (int kq = 0; kq < 32; kq++) {
            float4 wv = wr[kq];
            float4 hv = *(const float4*)&h2s[row][kq * 4];
            a = fmaf(wv.x, hv.x, fmaf(wv.y, hv.y, fmaf(wv.z, hv.z, fmaf(wv.w, hv.w, a))));
        }
        po = fmaf(leakyf_(a + bfc[j]), Wout[j], po);
    }
#pragma unroll
    for (int o = 1; o < 32; o <<= 1) po += __shfl_xor(po, o, 64);
    if (jj == 0) out[n0 + row] = 1.f / (1.f + __expf(-(po + bout[0])));
}

extern "C" void kernel_launch(void* const* d_in, const int* in_sizes, int n_in,
                              void* d_out, int out_size, void* d_ws, size_t ws_size,
                              hipStream_t stream) {
    const float* x = (const float*)d_in[0];
    const float* bn1_g = (const float*)d_in[1];
    const float* bn1_b = (const float*)d_in[2];
    const float* W_ih = (const float*)d_in[3];
    const float* W_hh = (const float*)d_in[4];
    const float* b_ih = (const float*)d_in[5];
    const float* b_hh = (const float*)d_in[6];
    const float* bn2_g = (const float*)d_in[7];
    const float* bn2_b = (const float*)d_in[8];
    const float* W_t = (const float*)d_in[9];
    const float* b_t = (const float*)d_in[10];
    const float* a = (const float*)d_in[11];
    const float* W_fc = (const float*)d_in[12];
    const float* b_fc = (const float*)d_in[13];
    const float* W_out = (const float*)d_in[14];
    const float* b_out = (const float*)d_in[15];
    float* ws = (float*)d_ws;
    float* out = (float*)d_out;

    hipMemsetAsync((char*)d_ws + SSUM * sizeof(float), 0, 392 * sizeof(float), stream);
    k_pre<<<1409, 256, 0, stream>>>(x, bn1_g, bn1_b, W_ih, W_hh, b_ih, b_hh, W_t, b_t, a, ws);
    k_lstm<<<NN / 16, 512, 0, stream>>>(bn2_g, bn2_b, ws);
    k_hbn<<<NN / 32, 256, 0, stream>>>(ws);
    k_attfc<<<NN / 16, 512, 0, stream>>>(W_fc, b_fc, W_out, b_out, ws, out);
}